// Round 11
// baseline (1517.657 us; speedup 1.0000x reference)
//
#include <hip/hip_runtime.h>
#include <hip/hip_bf16.h>

#define T_TOK 8192
#define D_DIM 1024
#define F_DIM 4096
#define E_NUM 8
#define BM 128
#define MAX_ROWS (2 * T_TOK + E_NUM * BM)   // 17408
#define NUM_RB (MAX_ROWS / BM)              // 136

typedef __hip_bfloat16 bf16;
using bf16x8  = __attribute__((ext_vector_type(8))) __bf16;
using float4v = __attribute__((ext_vector_type(4))) float;

// load one K-step's fragments straight from global (per-lane, MFMA layout):
// frag row = lane&15, 16B chunk = lane>>4. OFS in elements from current base.
#define LOADF(AARR, BARR, OFS)                                                 \
    _Pragma("unroll") for (int m_ = 0; m_ < 4; ++m_)                           \
        AARR[m_] = *(const bf16x8*)(aPtr[m_] + (OFS));                         \
    _Pragma("unroll") for (int n_ = 0; n_ < 4; ++n_)                           \
        BARR[n_] = *(const bf16x8*)(bPtr[n_] + (OFS));

#define MM(AARR, BARR)                                                         \
    _Pragma("unroll") for (int m_ = 0; m_ < 4; ++m_)                           \
        _Pragma("unroll") for (int n_ = 0; n_ < 4; ++n_)                       \
            acc[m_][n_] = __builtin_amdgcn_mfma_f32_16x16x32_bf16(             \
                AARR[m_], BARR[n_], acc[m_][n_], 0, 0, 0);

#define ADV(N)                                                                 \
    _Pragma("unroll") for (int m_ = 0; m_ < 4; ++m_) aPtr[m_] += (N);          \
    _Pragma("unroll") for (int n_ = 0; n_ < 4; ++n_) bPtr[n_] += (N);

// ---------------- x -> bf16 ----------------
__global__ __launch_bounds__(256) void xcvt_kernel(const float* __restrict__ x,
                                                   bf16* __restrict__ xb) {
    const int i = blockIdx.x * 256 + threadIdx.x;  // over T*D/4
    float4 v = ((const float4*)x)[i];
    bf16 tmp[4];
    tmp[0] = __float2bfloat16(v.x);
    tmp[1] = __float2bfloat16(v.y);
    tmp[2] = __float2bfloat16(v.z);
    tmp[3] = __float2bfloat16(v.w);
    ((ushort4*)xb)[i] = *(const ushort4*)tmp;
}

// ------- transpose+convert: src[e][M][N] f32 -> dst[e][N][M] bf16, 64x64 tiles -------
__global__ __launch_bounds__(256) void transpose_cvt(const float* __restrict__ src,
                                                     bf16* __restrict__ dst,
                                                     int M, int N) {
    __shared__ float tile[64][65];
    const int e = blockIdx.z;
    const float* s = src + (size_t)e * M * N;
    bf16* d = dst + (size_t)e * M * N;
    const int n0 = blockIdx.x * 64, m0 = blockIdx.y * 64;
    const int tx = threadIdx.x & 15, ty = threadIdx.x >> 4;
#pragma unroll
    for (int i = 0; i < 4; ++i) {
        const int r = ty + i * 16;
        const float4 v = *(const float4*)&s[(size_t)(m0 + r) * N + n0 + tx * 4];
        tile[r][tx * 4 + 0] = v.x;
        tile[r][tx * 4 + 1] = v.y;
        tile[r][tx * 4 + 2] = v.z;
        tile[r][tx * 4 + 3] = v.w;
    }
    __syncthreads();
#pragma unroll
    for (int i = 0; i < 4; ++i) {
        const int nc = ty + i * 16;
        bf16 o[4];
#pragma unroll
        for (int j = 0; j < 4; ++j) o[j] = __float2bfloat16(tile[tx * 4 + j][nc]);
        *(ushort4*)&d[(size_t)(n0 + nc) * M + m0 + tx * 4] = *(const ushort4*)o;
    }
}

// ---------------- router: logits (fp32), top-2, softmax, counts ----------------
__global__ __launch_bounds__(256) void router_kernel(
    const float* __restrict__ x, const float* __restrict__ Wg,
    const float* __restrict__ bg, int* __restrict__ top_idx,
    float* __restrict__ top_gate, int* __restrict__ counts) {
    __shared__ float wg_s[E_NUM][D_DIM];
    for (int i = threadIdx.x; i < D_DIM * E_NUM; i += 256)
        wg_s[i & 7][i >> 3] = Wg[i];
    __syncthreads();

    const int lane = threadIdx.x & 63;
    const int t = blockIdx.x * 4 + (threadIdx.x >> 6);
    float acc[E_NUM];
#pragma unroll
    for (int e = 0; e < E_NUM; ++e) acc[e] = 0.f;
    const float* xrow = x + (size_t)t * D_DIM;
    for (int d = lane; d < D_DIM; d += 64) {
        const float xv = xrow[d];
#pragma unroll
        for (int e = 0; e < E_NUM; ++e) acc[e] += xv * wg_s[e][d];
    }
#pragma unroll
    for (int off = 32; off > 0; off >>= 1) {
#pragma unroll
        for (int e = 0; e < E_NUM; ++e) acc[e] += __shfl_xor(acc[e], off, 64);
    }
    if (lane == 0) {
        float v[E_NUM];
#pragma unroll
        for (int e = 0; e < E_NUM; ++e) v[e] = acc[e] + bg[e];
        int i0 = 0;
#pragma unroll
        for (int e = 1; e < E_NUM; ++e)
            if (v[e] > v[i0]) i0 = e;
        int i1 = -1;
#pragma unroll
        for (int e = 0; e < E_NUM; ++e) {
            if (e == i0) continue;
            if (i1 < 0 || v[e] > v[i1]) i1 = e;
        }
        const float g0 = 1.f / (1.f + expf(v[i1] - v[i0]));
        top_idx[2 * t] = i0;
        top_idx[2 * t + 1] = i1;
        top_gate[2 * t] = g0;
        top_gate[2 * t + 1] = 1.f - g0;
        atomicAdd(&counts[i0], 1);
        atomicAdd(&counts[i1], 1);
    }
}

// ---------------- padded segment offsets ----------------
__global__ void offsets_kernel(const int* __restrict__ counts, int* __restrict__ offsets) {
    if (threadIdx.x == 0) {
        int off = 0;
#pragma unroll
        for (int e = 0; e < E_NUM; ++e) {
            offsets[e] = off;
            off += (counts[e] + BM - 1) / BM * BM;
        }
        offsets[E_NUM] = off;
    }
}

// ---------------- scatter tokens into expert segments ----------------
__global__ __launch_bounds__(256) void scatter_kernel(
    const int* __restrict__ top_idx, const float* __restrict__ top_gate,
    const int* __restrict__ offsets, int* __restrict__ cursors,
    int* __restrict__ tok_list, float* __restrict__ gate_list) {
    const int t = blockIdx.x * 256 + threadIdx.x;
    if (t >= T_TOK) return;
#pragma unroll
    for (int j = 0; j < 2; ++j) {
        const int e = top_idx[2 * t + j];
        const int pos = atomicAdd(&cursors[e], 1);
        const int slot = offsets[e] + pos;
        tok_list[slot] = t;
        gate_list[slot] = top_gate[2 * t + j];
    }
}

// ---------------- GEMM1: direct-to-register, no LDS tiles, no barriers -------
// 128x128 tile, 4 waves (wave = 64x64). Each lane loads its MFMA fragments
// straight from global/L2 (16x64B lines per load), 2-deep reg double-buffer.
__global__ __launch_bounds__(256, 3) void gemm1_kernel(
    const bf16* __restrict__ xb, const bf16* __restrict__ W1t,
    const float* __restrict__ b1, const int* __restrict__ tok_list,
    const int* __restrict__ offsets, bf16* __restrict__ hbuf) {
    __shared__ int toks[BM];

    const int NCB = F_DIM / 128;          // 32
    const int per = (NUM_RB * NCB) / 8;   // 544
    const int flat = blockIdx.x;
    const int sw = (flat & 7) * per + (flat >> 3);
    const int rb = sw / NCB, cb = sw % NCB;

    const int row0 = rb * BM;
    const int total = offsets[E_NUM];
    if (row0 >= total) return;
    int e = 0;
#pragma unroll
    for (int i = 1; i < E_NUM; ++i) e += (row0 >= offsets[i]) ? 1 : 0;

    const int tid = threadIdx.x;
    if (tid < BM) toks[tid] = tok_list[row0 + tid];
    __syncthreads();

    const int lane = tid & 63;
    const int w = tid >> 6;
    const int f0 = cb * 128;
    const int wrow = (w >> 1) * 64, wcol = (w & 1) * 64;
    const int fr = lane & 15, kc = (lane >> 4) * 8;

    const bf16* aPtr[4];
    const bf16* bPtr[4];
#pragma unroll
    for (int m = 0; m < 4; ++m) {
        int t = toks[wrow + m * 16 + fr];
        if (t < 0) t = 0;
        aPtr[m] = xb + (size_t)t * D_DIM + kc;
    }
#pragma unroll
    for (int n = 0; n < 4; ++n)
        bPtr[n] = W1t + ((size_t)e * F_DIM + f0 + wcol + n * 16 + fr) * D_DIM + kc;

    float4v acc[4][4];
#pragma unroll
    for (int m = 0; m < 4; ++m)
#pragma unroll
        for (int n = 0; n < 4; ++n)
#pragma unroll
            for (int r = 0; r < 4; ++r) acc[m][n][r] = 0.f;

    bf16x8 a0[4], b0[4], a1[4], b1r[4];
    const int NKT = D_DIM / 32;  // 32, even
    LOADF(a0, b0, 0)
    for (int kt = 0; kt < NKT - 2; kt += 2) {
        LOADF(a1, b1r, 32)
        MM(a0, b0)
        ADV(64)
        LOADF(a0, b0, 0)
        MM(a1, b1r)
    }
    LOADF(a1, b1r, 32)
    MM(a0, b0)
    MM(a1, b1r)

#pragma unroll
    for (int n = 0; n < 4; ++n) {
        const int gcol = f0 + wcol + n * 16 + fr;
        const float bias = b1[e * F_DIM + gcol];
#pragma unroll
        for (int m = 0; m < 4; ++m) {
#pragma unroll
            for (int r = 0; r < 4; ++r) {
                const int grow = row0 + wrow + m * 16 + (lane >> 4) * 4 + r;
                float v = acc[m][n][r] + bias;
                v = fmaxf(v, 0.f);
                hbuf[(size_t)grow * F_DIM + gcol] = __float2bfloat16(v);
            }
        }
    }
}

// ---------------- GEMM2: direct-to-register, scatter-add epilogue ------------
__global__ __launch_bounds__(256, 3) void gemm2_kernel(
    const bf16* __restrict__ hbuf, const bf16* __restrict__ W2t,
    const float* __restrict__ b2, const int* __restrict__ tok_list,
    const float* __restrict__ gate_list, const int* __restrict__ offsets,
    float* __restrict__ out) {
    __shared__ int toks[BM];
    __shared__ float gates_s[BM];

    const int NCB = D_DIM / 128;          // 8
    const int per = (NUM_RB * NCB) / 8;   // 136
    const int flat = blockIdx.x;
    const int sw = (flat & 7) * per + (flat >> 3);
    const int rb = sw / NCB, cb = sw % NCB;

    const int row0 = rb * BM;
    const int total = offsets[E_NUM];
    if (row0 >= total) return;
    int e = 0;
#pragma unroll
    for (int i = 1; i < E_NUM; ++i) e += (row0 >= offsets[i]) ? 1 : 0;

    const int tid = threadIdx.x;
    if (tid < BM) {
        int t = tok_list[row0 + tid];
        toks[tid] = t;
        gates_s[tid] = (t >= 0) ? gate_list[row0 + tid] : 0.f;
    }
    __syncthreads();

    const int lane = tid & 63;
    const int w = tid >> 6;
    const int d0 = cb * 128;
    const int wrow = (w >> 1) * 64, wcol = (w & 1) * 64;
    const int fr = lane & 15, kc = (lane >> 4) * 8;

    const bf16* aPtr[4];
    const bf16* bPtr[4];
#pragma unroll
    for (int m = 0; m < 4; ++m)
        aPtr[m] = hbuf + (size_t)(row0 + wrow + m * 16 + fr) * F_DIM + kc;
#pragma unroll
    for (int n = 0; n < 4; ++n)
        bPtr[n] = W2t + ((size_t)e * D_DIM + d0 + wcol + n * 16 + fr) * F_DIM + kc;

    float4v acc[4][4];
#pragma unroll
    for (int m = 0; m < 4; ++m)
#pragma unroll
        for (int n = 0; n < 4; ++n)
#pragma unroll
            for (int r = 0; r < 4; ++r) acc[m][n][r] = 0.f;

    bf16x8 a0[4], b0[4], a1[4], b1r[4];
    const int NKT = F_DIM / 32;  // 128, even
    LOADF(a0, b0, 0)
    for (int kt = 0; kt < NKT - 2; kt += 2) {
        LOADF(a1, b1r, 32)
        MM(a0, b0)
        ADV(64)
        LOADF(a0, b0, 0)
        MM(a1, b1r)
    }
    LOADF(a1, b1r, 32)
    MM(a0, b0)
    MM(a1, b1r)

#pragma unroll
    for (int n = 0; n < 4; ++n) {
        const int gcol = d0 + wcol + n * 16 + fr;
        const float bias = b2[e * D_DIM + gcol];
#pragma unroll
        for (int m = 0; m < 4; ++m) {
#pragma unroll
            for (int r = 0; r < 4; ++r) {
                const int lrow = wrow + m * 16 + (lane >> 4) * 4 + r;
                const int t = toks[lrow];
                if (t >= 0) {
                    const float v = (acc[m][n][r] + bias) * gates_s[lrow];
                    atomicAdd(&out[(size_t)t * D_DIM + gcol], v);
                }
            }
        }
    }
}

extern "C" void kernel_launch(void* const* d_in, const int* in_sizes, int n_in,
                              void* d_out, int out_size, void* d_ws, size_t ws_size,
                              hipStream_t stream) {
    const float* x = (const float*)d_in[0];
    const float* Wg = (const float*)d_in[1];
    const float* bg = (const float*)d_in[2];
    const float* W1 = (const float*)d_in[3];
    const float* b1 = (const float*)d_in[4];
    const float* W2 = (const float*)d_in[5];
    const float* b2 = (const float*)d_in[6];
    float* out = (float*)d_out;

    char* ws = (char*)d_ws;
    int* counts = (int*)(ws + 0);       // 8 ints
    int* cursors = (int*)(ws + 32);     // 8 ints
    int* offsets = (int*)(ws + 64);     // 9 ints
    int* top_idx = (int*)(ws + 256);                     // T*2 ints
    float* top_gate = (float*)(ws + 256 + 65536);        // T*2 floats
    int* tok_list = (int*)(ws + 256 + 2 * 65536);        // MAX_ROWS ints
    float* gate_list = (float*)(ws + 256 + 2 * 65536 + 69632);
    size_t off = 256 + 2 * 65536 + 2 * 69632;            // 270592, 256-aligned
    bf16* xb = (bf16*)(ws + off);
    off += (size_t)T_TOK * D_DIM * 2;
    bf16* W1t = (bf16*)(ws + off);
    off += (size_t)E_NUM * D_DIM * F_DIM * 2;
    bf16* W2t = (bf16*)(ws + off);
    off += (size_t)E_NUM * D_DIM * F_DIM * 2;
    bf16* hbuf = (bf16*)(ws + off);

    hipMemsetAsync(d_out, 0, (size_t)T_TOK * D_DIM * sizeof(float), stream);
    hipMemsetAsync(ws, 0, 64, stream);                       // counts + cursors
    hipMemsetAsync(tok_list, 0xFF, (size_t)MAX_ROWS * 4, stream);  // -1 sentinels

    xcvt_kernel<<<T_TOK * D_DIM / 4 / 256, 256, 0, stream>>>(x, xb);
    transpose_cvt<<<dim3(F_DIM / 64, D_DIM / 64, E_NUM), dim3(256), 0, stream>>>(
        W1, W1t, D_DIM, F_DIM);
    transpose_cvt<<<dim3(D_DIM / 64, F_DIM / 64, E_NUM), dim3(256), 0, stream>>>(
        W2, W2t, F_DIM, D_DIM);
    router_kernel<<<T_TOK / 4, 256, 0, stream>>>(x, Wg, bg, top_idx, top_gate, counts);
    offsets_kernel<<<1, 64, 0, stream>>>(counts, offsets);
    scatter_kernel<<<T_TOK / 256, 256, 0, stream>>>(top_idx, top_gate, offsets, cursors,
                                                    tok_list, gate_list);
    gemm1_kernel<<<NUM_RB * (F_DIM / 128), 256, 0, stream>>>(xb, W1t, b1, tok_list,
                                                             offsets, hbuf);
    gemm2_kernel<<<NUM_RB * (D_DIM / 128), 256, 0, stream>>>(hbuf, W2t, b2, tok_list,
                                                             gate_list, offsets, out);
}

// Round 13
// 947.813 us; speedup vs baseline: 1.6012x; 1.6012x over previous
//
#include <hip/hip_runtime.h>
#include <hip/hip_bf16.h>

#define T_TOK 8192
#define D_DIM 1024
#define F_DIM 4096
#define E_NUM 8
#define BM 128
#define MAX_ROWS (2 * T_TOK + E_NUM * BM)   // 17408
#define NUM_RB (MAX_ROWS / BM)              // 136

typedef __hip_bfloat16 bf16;
using bf16x8  = __attribute__((ext_vector_type(8))) __bf16;
using float4v = __attribute__((ext_vector_type(4))) float;

// async global->LDS, 16B per lane; dest = uniform base + lane*16
__device__ inline void gl_lds16(const bf16* g, bf16* l) {
    __builtin_amdgcn_global_load_lds(
        (const __attribute__((address_space(1))) void*)g,
        (__attribute__((address_space(3))) void*)l, 16, 0, 0);
}

// R4-proven phase, adapted to 128x64 tile (wave = 64x32): counted vmcnt,
// pinned reads, 2 barriers, stage(kt+2) after the second barrier.
#define PH(WAITSTR, CA, CB, DOSTAGE, KST)                                      \
    do {                                                                       \
        asm volatile("s_waitcnt " WAITSTR ::: "memory");                       \
        __builtin_amdgcn_s_barrier();                                          \
        bf16x8 af[4], bfr[2];                                                  \
        _Pragma("unroll")                                                      \
        for (int m_ = 0; m_ < 4; ++m_)                                         \
            af[m_] = *(const bf16x8*)&(CA)[(wrow + m_ * 16 + fr) * 32 + fkk];  \
        _Pragma("unroll")                                                      \
        for (int n_ = 0; n_ < 2; ++n_)                                         \
            bfr[n_] = *(const bf16x8*)&(CB)[(wcol + n_ * 16 + fr) * 32 + fkk]; \
        asm volatile("s_waitcnt lgkmcnt(0)" ::: "memory");                     \
        __builtin_amdgcn_sched_barrier(0);                                     \
        __builtin_amdgcn_s_barrier();                                          \
        if (DOSTAGE) stage(KST, CA, CB);                                       \
        __builtin_amdgcn_s_setprio(1);                                         \
        _Pragma("unroll")                                                      \
        for (int m_ = 0; m_ < 4; ++m_)                                         \
            _Pragma("unroll")                                                  \
            for (int n_ = 0; n_ < 2; ++n_)                                     \
                acc[m_][n_] = __builtin_amdgcn_mfma_f32_16x16x32_bf16(         \
                    af[m_], bfr[n_], acc[m_][n_], 0, 0, 0);                    \
        __builtin_amdgcn_s_setprio(0);                                         \
    } while (0)

// ---------------- x -> bf16 ----------------
__global__ __launch_bounds__(256) void xcvt_kernel(const float* __restrict__ x,
                                                   bf16* __restrict__ xb) {
    const int i = blockIdx.x * 256 + threadIdx.x;  // over T*D/4
    float4 v = ((const float4*)x)[i];
    bf16 tmp[4];
    tmp[0] = __float2bfloat16(v.x);
    tmp[1] = __float2bfloat16(v.y);
    tmp[2] = __float2bfloat16(v.z);
    tmp[3] = __float2bfloat16(v.w);
    ((ushort4*)xb)[i] = *(const ushort4*)tmp;
}

// ------- transpose+convert: src[e][M][N] f32 -> dst[e][N][M] bf16, 64x64 tiles -------
__global__ __launch_bounds__(256) void transpose_cvt(const float* __restrict__ src,
                                                     bf16* __restrict__ dst,
                                                     int M, int N) {
    __shared__ float tile[64][65];
    const int e = blockIdx.z;
    const float* s = src + (size_t)e * M * N;
    bf16* d = dst + (size_t)e * M * N;
    const int n0 = blockIdx.x * 64, m0 = blockIdx.y * 64;
    const int tx = threadIdx.x & 15, ty = threadIdx.x >> 4;
#pragma unroll
    for (int i = 0; i < 4; ++i) {
        const int r = ty + i * 16;
        const float4 v = *(const float4*)&s[(size_t)(m0 + r) * N + n0 + tx * 4];
        tile[r][tx * 4 + 0] = v.x;
        tile[r][tx * 4 + 1] = v.y;
        tile[r][tx * 4 + 2] = v.z;
        tile[r][tx * 4 + 3] = v.w;
    }
    __syncthreads();
#pragma unroll
    for (int i = 0; i < 4; ++i) {
        const int nc = ty + i * 16;
        bf16 o[4];
#pragma unroll
        for (int j = 0; j < 4; ++j) o[j] = __float2bfloat16(tile[tx * 4 + j][nc]);
        *(ushort4*)&d[(size_t)(n0 + nc) * M + m0 + tx * 4] = *(const ushort4*)o;
    }
}

// ---------------- router: logits (fp32), top-2, softmax, counts ----------------
__global__ __launch_bounds__(256) void router_kernel(
    const float* __restrict__ x, const float* __restrict__ Wg,
    const float* __restrict__ bg, int* __restrict__ top_idx,
    float* __restrict__ top_gate, int* __restrict__ counts) {
    __shared__ float wg_s[E_NUM][D_DIM];
    for (int i = threadIdx.x; i < D_DIM * E_NUM; i += 256)
        wg_s[i & 7][i >> 3] = Wg[i];
    __syncthreads();

    const int lane = threadIdx.x & 63;
    const int t = blockIdx.x * 4 + (threadIdx.x >> 6);
    float acc[E_NUM];
#pragma unroll
    for (int e = 0; e < E_NUM; ++e) acc[e] = 0.f;
    const float* xrow = x + (size_t)t * D_DIM;
    for (int d = lane; d < D_DIM; d += 64) {
        const float xv = xrow[d];
#pragma unroll
        for (int e = 0; e < E_NUM; ++e) acc[e] += xv * wg_s[e][d];
    }
#pragma unroll
    for (int off = 32; off > 0; off >>= 1) {
#pragma unroll
        for (int e = 0; e < E_NUM; ++e) acc[e] += __shfl_xor(acc[e], off, 64);
    }
    if (lane == 0) {
        float v[E_NUM];
#pragma unroll
        for (int e = 0; e < E_NUM; ++e) v[e] = acc[e] + bg[e];
        int i0 = 0;
#pragma unroll
        for (int e = 1; e < E_NUM; ++e)
            if (v[e] > v[i0]) i0 = e;
        int i1 = -1;
#pragma unroll
        for (int e = 0; e < E_NUM; ++e) {
            if (e == i0) continue;
            if (i1 < 0 || v[e] > v[i1]) i1 = e;
        }
        const float g0 = 1.f / (1.f + expf(v[i1] - v[i0]));
        top_idx[2 * t] = i0;
        top_idx[2 * t + 1] = i1;
        top_gate[2 * t] = g0;
        top_gate[2 * t + 1] = 1.f - g0;
        atomicAdd(&counts[i0], 1);
        atomicAdd(&counts[i1], 1);
    }
}

// ---------------- padded segment offsets ----------------
__global__ void offsets_kernel(const int* __restrict__ counts, int* __restrict__ offsets) {
    if (threadIdx.x == 0) {
        int off = 0;
#pragma unroll
        for (int e = 0; e < E_NUM; ++e) {
            offsets[e] = off;
            off += (counts[e] + BM - 1) / BM * BM;
        }
        offsets[E_NUM] = off;
    }
}

// ---------------- scatter tokens into expert segments ----------------
__global__ __launch_bounds__(256) void scatter_kernel(
    const int* __restrict__ top_idx, const float* __restrict__ top_gate,
    const int* __restrict__ offsets, int* __restrict__ cursors,
    int* __restrict__ tok_list, float* __restrict__ gate_list) {
    const int t = blockIdx.x * 256 + threadIdx.x;
    if (t >= T_TOK) return;
#pragma unroll
    for (int j = 0; j < 2; ++j) {
        const int e = top_idx[2 * t + j];
        const int pos = atomicAdd(&cursors[e], 1);
        const int slot = offsets[e] + pos;
        tok_list[slot] = t;
        gate_list[slot] = top_gate[2 * t + j];
    }
}

// ---------------- GEMM1: 128x64 tile, 6 blocks/CU, R4 schedule ----------------
__global__ __launch_bounds__(256, 6) void gemm1_kernel(
    const bf16* __restrict__ xb, const bf16* __restrict__ W1t,
    const float* __restrict__ b1, const int* __restrict__ tok_list,
    const int* __restrict__ offsets, bf16* __restrict__ hbuf) {
    __shared__ bf16 As0[128 * 32];
    __shared__ bf16 As1[128 * 32];
    __shared__ bf16 Bs0[64 * 32];
    __shared__ bf16 Bs1[64 * 32];
    __shared__ int toks[BM];

    const int NCB = F_DIM / 64;           // 64
    const int per = (NUM_RB * NCB) / 8;   // 1088
    const int flat = blockIdx.x;
    const int sw = (flat & 7) * per + (flat >> 3);
    const int rb = sw / NCB, cb = sw % NCB;

    const int row0 = rb * BM;
    const int total = offsets[E_NUM];
    if (row0 >= total) return;
    int e = 0;
#pragma unroll
    for (int i = 1; i < E_NUM; ++i) e += (row0 >= offsets[i]) ? 1 : 0;

    const int tid = threadIdx.x;
    if (tid < BM) toks[tid] = tok_list[row0 + tid];
    __syncthreads();   // full drain: vmcnt henceforth counts only stage loads

    const int lane = tid & 63;
    const int w = tid >> 6;
    const int f0 = cb * 64;

    // staging rows: A issue0 rows w*16+(lane>>2), issue1 rows 64+...; B single issue
    const int r0 = w * 16 + (lane >> 2);
    const int c16 = (lane & 3) ^ ((lane >> 3) & 3);   // T2 pre-swizzled source
    int t0 = toks[r0]; if (t0 < 0) t0 = 0;
    int t1 = toks[64 + r0]; if (t1 < 0) t1 = 0;
    const bf16* aP0 = xb + (size_t)t0 * D_DIM + c16 * 8;
    const bf16* aP1 = xb + (size_t)t1 * D_DIM + c16 * 8;
    const bf16* bP0 = W1t + ((size_t)e * F_DIM + f0 + r0) * D_DIM + c16 * 8;

    const unsigned dO0 = __builtin_amdgcn_readfirstlane(w * 1024);
    const unsigned dO1 = __builtin_amdgcn_readfirstlane(4096 + w * 1024);  // rows 64..127

    const int wrow = (w >> 1) * 64, wcol = (w & 1) * 32;
    const int fr = lane & 15;
    const int fkk = 8 * ((lane >> 4) ^ ((lane >> 1) & 3));

    float4v acc[4][2];
#pragma unroll
    for (int m = 0; m < 4; ++m)
#pragma unroll
        for (int n = 0; n < 2; ++n)
#pragma unroll
            for (int r = 0; r < 4; ++r) acc[m][n][r] = 0.f;

    auto stage = [&](int kt, bf16* A, bf16* B) {
        const int ko = kt * 32;
        gl_lds16(aP0 + ko, (bf16*)((char*)A + dO0));
        gl_lds16(aP1 + ko, (bf16*)((char*)A + dO1));
        gl_lds16(bP0 + ko, (bf16*)((char*)B + dO0));
    };

    const int NKT = D_DIM / 32;  // 32
    stage(0, As0, Bs0);
    stage(1, As1, Bs1);
    for (int kt = 0; kt < NKT - 2; kt += 2) {
        PH("vmcnt(3)", As0, Bs0, true, kt + 2);
        PH("vmcnt(3)", As1, Bs1, true, kt + 3);
    }
    PH("vmcnt(3)", As0, Bs0, false, 0);
    PH("vmcnt(0)", As1, Bs1, false, 0);

#pragma unroll
    for (int n = 0; n < 2; ++n) {
        const int gcol = f0 + wcol + n * 16 + fr;
        const float bias = b1[e * F_DIM + gcol];
#pragma unroll
        for (int m = 0; m < 4; ++m) {
#pragma unroll
            for (int r = 0; r < 4; ++r) {
                const int grow = row0 + wrow + m * 16 + (lane >> 4) * 4 + r;
                float v = acc[m][n][r] + bias;
                v = fmaxf(v, 0.f);
                hbuf[(size_t)grow * F_DIM + gcol] = __float2bfloat16(v);
            }
        }
    }
}

// ---------------- GEMM2: 128x64 tile, 6 blocks/CU, scatter-add epilogue -------
__global__ __launch_bounds__(256, 6) void gemm2_kernel(
    const bf16* __restrict__ hbuf, const bf16* __restrict__ W2t,
    const float* __restrict__ b2, const int* __restrict__ tok_list,
    const float* __restrict__ gate_list, const int* __restrict__ offsets,
    float* __restrict__ out) {
    __shared__ bf16 As0[128 * 32];
    __shared__ bf16 As1[128 * 32];
    __shared__ bf16 Bs0[64 * 32];
    __shared__ bf16 Bs1[64 * 32];
    __shared__ int toks[BM];
    __shared__ float gates_s[BM];

    const int NCB = D_DIM / 64;           // 16
    const int per = (NUM_RB * NCB) / 8;   // 272
    const int flat = blockIdx.x;
    const int sw = (flat & 7) * per + (flat >> 3);
    const int rb = sw / NCB, cb = sw % NCB;

    const int row0 = rb * BM;
    const int total = offsets[E_NUM];
    if (row0 >= total) return;
    int e = 0;
#pragma unroll
    for (int i = 1; i < E_NUM; ++i) e += (row0 >= offsets[i]) ? 1 : 0;

    const int tid = threadIdx.x;
    if (tid < BM) {
        int t = tok_list[row0 + tid];
        toks[tid] = t;
        gates_s[tid] = (t >= 0) ? gate_list[row0 + tid] : 0.f;
    }
    __syncthreads();

    const int lane = tid & 63;
    const int w = tid >> 6;
    const int d0 = cb * 64;

    const int r0 = w * 16 + (lane >> 2);
    const int c16 = (lane & 3) ^ ((lane >> 3) & 3);
    const bf16* aP0 = hbuf + (size_t)(row0 + r0) * F_DIM + c16 * 8;
    const bf16* aP1 = hbuf + (size_t)(row0 + 64 + r0) * F_DIM + c16 * 8;
    const bf16* bP0 = W2t + ((size_t)e * D_DIM + d0 + r0) * F_DIM + c16 * 8;

    const unsigned dO0 = __builtin_amdgcn_readfirstlane(w * 1024);
    const unsigned dO1 = __builtin_amdgcn_readfirstlane(4096 + w * 1024);  // rows 64..127

    const int wrow = (w >> 1) * 64, wcol = (w & 1) * 32;
    const int fr = lane & 15;
    const int fkk = 8 * ((lane >> 4) ^ ((lane >> 1) & 3));

    float4v acc[4][2];
#pragma unroll
    for (int m = 0; m < 4; ++m)
#pragma unroll
        for (int n = 0; n < 2; ++n)
#pragma unroll
            for (int r = 0; r < 4; ++r) acc[m][n][r] = 0.f;

    auto stage = [&](int kt, bf16* A, bf16* B) {
        const int ko = kt * 32;
        gl_lds16(aP0 + ko, (bf16*)((char*)A + dO0));
        gl_lds16(aP1 + ko, (bf16*)((char*)A + dO1));
        gl_lds16(bP0 + ko, (bf16*)((char*)B + dO0));
    };

    const int NKT = F_DIM / 32;  // 128
    stage(0, As0, Bs0);
    stage(1, As1, Bs1);
    for (int kt = 0; kt < NKT - 2; kt += 2) {
        PH("vmcnt(3)", As0, Bs0, true, kt + 2);
        PH("vmcnt(3)", As1, Bs1, true, kt + 3);
    }
    PH("vmcnt(3)", As0, Bs0, false, 0);
    PH("vmcnt(0)", As1, Bs1, false, 0);

#pragma unroll
    for (int n = 0; n < 2; ++n) {
        const int gcol = d0 + wcol + n * 16 + fr;
        const float bias = b2[e * D_DIM + gcol];
#pragma unroll
        for (int m = 0; m < 4; ++m) {
#pragma unroll
            for (int r = 0; r < 4; ++r) {
                const int lrow = wrow + m * 16 + (lane >> 4) * 4 + r;
                const int t = toks[lrow];
                if (t >= 0) {
                    const float v = (acc[m][n][r] + bias) * gates_s[lrow];
                    atomicAdd(&out[(size_t)t * D_DIM + gcol], v);
                }
            }
        }
    }
}

extern "C" void kernel_launch(void* const* d_in, const int* in_sizes, int n_in,
                              void* d_out, int out_size, void* d_ws, size_t ws_size,
                              hipStream_t stream) {
    const float* x = (const float*)d_in[0];
    const float* Wg = (const float*)d_in[1];
    const float* bg = (const float*)d_in[2];
    const float* W1 = (const float*)d_in[3];
    const float* b1 = (const float*)d_in[4];
    const float* W2 = (const float*)d_in[5];
    const float* b2 = (const float*)d_in[6];
    float* out = (float*)d_out;

    char* ws = (char*)d_ws;
    int* counts = (int*)(ws + 0);       // 8 ints
    int* cursors = (int*)(ws + 32);     // 8 ints
    int* offsets = (int*)(ws + 64);     // 9 ints
    int* top_idx = (int*)(ws + 256);                     // T*2 ints
    float* top_gate = (float*)(ws + 256 + 65536);        // T*2 floats
    int* tok_list = (int*)(ws + 256 + 2 * 65536);        // MAX_ROWS ints
    float* gate_list = (float*)(ws + 256 + 2 * 65536 + 69632);
    size_t off = 256 + 2 * 65536 + 2 * 69632;            // 270592, 256-aligned
    bf16* xb = (bf16*)(ws + off);
    off += (size_t)T_TOK * D_DIM * 2;
    bf16* W1t = (bf16*)(ws + off);
    off += (size_t)E_NUM * D_DIM * F_DIM * 2;
    bf16* W2t = (bf16*)(ws + off);
    off += (size_t)E_NUM * D_DIM * F_DIM * 2;
    bf16* hbuf = (bf16*)(ws + off);

    hipMemsetAsync(d_out, 0, (size_t)T_TOK * D_DIM * sizeof(float), stream);
    hipMemsetAsync(ws, 0, 64, stream);                       // counts + cursors
    hipMemsetAsync(tok_list, 0xFF, (size_t)MAX_ROWS * 4, stream);  // -1 sentinels

    xcvt_kernel<<<T_TOK * D_DIM / 4 / 256, 256, 0, stream>>>(x, xb);
    transpose_cvt<<<dim3(F_DIM / 64, D_DIM / 64, E_NUM), dim3(256), 0, stream>>>(
        W1, W1t, D_DIM, F_DIM);
    transpose_cvt<<<dim3(D_DIM / 64, F_DIM / 64, E_NUM), dim3(256), 0, stream>>>(
        W2, W2t, F_DIM, D_DIM);
    router_kernel<<<T_TOK / 4, 256, 0, stream>>>(x, Wg, bg, top_idx, top_gate, counts);
    offsets_kernel<<<1, 64, 0, stream>>>(counts, offsets);
    scatter_kernel<<<T_TOK / 256, 256, 0, stream>>>(top_idx, top_gate, offsets, cursors,
                                                    tok_list, gate_list);
    gemm1_kernel<<<NUM_RB * (F_DIM / 64), 256, 0, stream>>>(xb, W1t, b1, tok_list,
                                                            offsets, hbuf);
    gemm2_kernel<<<NUM_RB * (D_DIM / 64), 256, 0, stream>>>(hbuf, W2t, b2, tok_list,
                                                            gate_list, offsets, out);
}

// Round 14
// 803.595 us; speedup vs baseline: 1.8886x; 1.1795x over previous
//
#include <hip/hip_runtime.h>
#include <hip/hip_bf16.h>

#define T_TOK 8192
#define D_DIM 1024
#define F_DIM 4096
#define E_NUM 8
#define BM 128
#define MAX_ROWS (2 * T_TOK + E_NUM * BM)   // 17408
#define NUM_RB (MAX_ROWS / BM)              // 136

typedef __hip_bfloat16 bf16;
using bf16x8  = __attribute__((ext_vector_type(8))) __bf16;
using float4v = __attribute__((ext_vector_type(4))) float;

// async global->LDS, 16B per lane; dest = uniform base + lane*16
__device__ inline void gl_lds16(const bf16* g, bf16* l) {
    __builtin_amdgcn_global_load_lds(
        (const __attribute__((address_space(1))) void*)g,
        (__attribute__((address_space(3))) void*)l, 16, 0, 0);
}

// R4 phase: counted vmcnt, pinned reads, 2 barriers, stage after 2nd barrier.
#define PH(WAITSTR, CA, CB, DOSTAGE, KST)                                      \
    do {                                                                       \
        asm volatile("s_waitcnt " WAITSTR ::: "memory");                       \
        __builtin_amdgcn_s_barrier();                                          \
        bf16x8 af[4], bfr[4];                                                  \
        _Pragma("unroll")                                                      \
        for (int m_ = 0; m_ < 4; ++m_)                                         \
            af[m_] = *(const bf16x8*)&(CA)[(wrow + m_ * 16 + fr) * 32 + fkk];  \
        _Pragma("unroll")                                                      \
        for (int n_ = 0; n_ < 4; ++n_)                                         \
            bfr[n_] = *(const bf16x8*)&(CB)[(wcol + n_ * 16 + fr) * 32 + fkk]; \
        asm volatile("s_waitcnt lgkmcnt(0)" ::: "memory");                     \
        __builtin_amdgcn_sched_barrier(0);                                     \
        __builtin_amdgcn_s_barrier();                                          \
        if (DOSTAGE) stage(KST, CA, CB);                                       \
        __builtin_amdgcn_s_setprio(1);                                         \
        _Pragma("unroll")                                                      \
        for (int m_ = 0; m_ < 4; ++m_)                                         \
            _Pragma("unroll")                                                  \
            for (int n_ = 0; n_ < 4; ++n_)                                     \
                acc[m_][n_] = __builtin_amdgcn_mfma_f32_16x16x32_bf16(         \
                    af[m_], bfr[n_], acc[m_][n_], 0, 0, 0);                    \
        __builtin_amdgcn_s_setprio(0);                                         \
    } while (0)

// ---- fused transpose+convert for BOTH weights in one dispatch ----
// flat < 8192: W1 (e, M=D, N=F); else W2 (e, M=F, N=D). 64x64 f32->bf16^T tiles.
__global__ __launch_bounds__(256) void transpose_both(
    const float* __restrict__ W1, bf16* __restrict__ W1t,
    const float* __restrict__ W2, bf16* __restrict__ W2t) {
    __shared__ float tile[64][65];
    const int flat = blockIdx.x;
    const float* s;
    bf16* d;
    int M, N, n0, m0;
    if (flat < 8192) {
        const int e = flat >> 10, rem = flat & 1023;
        M = D_DIM; N = F_DIM;
        n0 = (rem & 63) * 64; m0 = (rem >> 6) * 64;
        s = W1 + (size_t)e * M * N;
        d = W1t + (size_t)e * M * N;
    } else {
        const int f2 = flat - 8192;
        const int e = f2 >> 10, rem = f2 & 1023;
        M = F_DIM; N = D_DIM;
        n0 = (rem & 15) * 64; m0 = (rem >> 4) * 64;
        s = W2 + (size_t)e * M * N;
        d = W2t + (size_t)e * M * N;
    }
    const int tx = threadIdx.x & 15, ty = threadIdx.x >> 4;
#pragma unroll
    for (int i = 0; i < 4; ++i) {
        const int r = ty + i * 16;
        const float4 v = *(const float4*)&s[(size_t)(m0 + r) * N + n0 + tx * 4];
        tile[r][tx * 4 + 0] = v.x;
        tile[r][tx * 4 + 1] = v.y;
        tile[r][tx * 4 + 2] = v.z;
        tile[r][tx * 4 + 3] = v.w;
    }
    __syncthreads();
#pragma unroll
    for (int i = 0; i < 4; ++i) {
        const int nc = ty + i * 16;
        bf16 o[4];
#pragma unroll
        for (int j = 0; j < 4; ++j) o[j] = __float2bfloat16(tile[tx * 4 + j][nc]);
        *(ushort4*)&d[(size_t)(n0 + nc) * M + m0 + tx * 4] = *(const ushort4*)o;
    }
}

// ---- router + x->bf16 fused (one pass over x per block's 4 rows) ----
__global__ __launch_bounds__(256) void router_xcvt_kernel(
    const float* __restrict__ x, const float* __restrict__ Wg,
    const float* __restrict__ bg, int* __restrict__ top_idx,
    float* __restrict__ top_gate, int* __restrict__ counts,
    bf16* __restrict__ xb) {
    __shared__ float wg_s[E_NUM][D_DIM];
    for (int i = threadIdx.x; i < D_DIM * E_NUM; i += 256)
        wg_s[i & 7][i >> 3] = Wg[i];
    __syncthreads();

    const int lane = threadIdx.x & 63;
    const int t = blockIdx.x * 4 + (threadIdx.x >> 6);
    float acc[E_NUM];
#pragma unroll
    for (int e = 0; e < E_NUM; ++e) acc[e] = 0.f;
    const float* xrow = x + (size_t)t * D_DIM;
    for (int d = lane; d < D_DIM; d += 64) {
        const float xv = xrow[d];
#pragma unroll
        for (int e = 0; e < E_NUM; ++e) acc[e] += xv * wg_s[e][d];
    }
#pragma unroll
    for (int off = 32; off > 0; off >>= 1) {
#pragma unroll
        for (int e = 0; e < E_NUM; ++e) acc[e] += __shfl_xor(acc[e], off, 64);
    }
    if (lane == 0) {
        float v[E_NUM];
#pragma unroll
        for (int e = 0; e < E_NUM; ++e) v[e] = acc[e] + bg[e];
        int i0 = 0;
#pragma unroll
        for (int e = 1; e < E_NUM; ++e)
            if (v[e] > v[i0]) i0 = e;
        int i1 = -1;
#pragma unroll
        for (int e = 0; e < E_NUM; ++e) {
            if (e == i0) continue;
            if (i1 < 0 || v[e] > v[i1]) i1 = e;
        }
        const float g0 = 1.f / (1.f + expf(v[i1] - v[i0]));
        top_idx[2 * t] = i0;
        top_idx[2 * t + 1] = i1;
        top_gate[2 * t] = g0;
        top_gate[2 * t + 1] = 1.f - g0;
        atomicAdd(&counts[i0], 1);
        atomicAdd(&counts[i1], 1);
    }
    // fused x->bf16 for this block's 4 rows (x slab is L2-hot)
    const float4* xs = (const float4*)(x + (size_t)blockIdx.x * 4 * D_DIM);
    ushort4* xd = (ushort4*)(xb + (size_t)blockIdx.x * 4 * D_DIM);
    for (int i = threadIdx.x; i < D_DIM; i += 256) {   // 4*1024/4 = 1024 float4
        float4 v = xs[i];
        bf16 tmp[4];
        tmp[0] = __float2bfloat16(v.x);
        tmp[1] = __float2bfloat16(v.y);
        tmp[2] = __float2bfloat16(v.z);
        tmp[3] = __float2bfloat16(v.w);
        xd[i] = *(const ushort4*)tmp;
    }
}

// ---- scatter with inline offsets (prefix over counts; block 0 publishes) ----
__global__ __launch_bounds__(256) void scatter_kernel(
    const int* __restrict__ top_idx, const float* __restrict__ top_gate,
    const int* __restrict__ counts, int* __restrict__ offsets,
    int* __restrict__ cursors, int* __restrict__ tok_list,
    float* __restrict__ gate_list) {
    int offs[E_NUM + 1];
    int o = 0;
#pragma unroll
    for (int e = 0; e < E_NUM; ++e) {
        offs[e] = o;
        o += (counts[e] + BM - 1) / BM * BM;
    }
    offs[E_NUM] = o;
    if (blockIdx.x == 0 && threadIdx.x < E_NUM + 1) offsets[threadIdx.x] = offs[threadIdx.x];

    const int t = blockIdx.x * 256 + threadIdx.x;
    if (t >= T_TOK) return;
#pragma unroll
    for (int j = 0; j < 2; ++j) {
        const int e = top_idx[2 * t + j];
        const int pos = atomicAdd(&cursors[e], 1);
        const int slot = offs[e] + pos;
        tok_list[slot] = t;
        gate_list[slot] = top_gate[2 * t + j];
    }
}

// ---------------- GEMM1 (exact R4): 128², 2-buf counted vmcnt ----------------
__global__ __launch_bounds__(256, 4) void gemm1_kernel(
    const bf16* __restrict__ xb, const bf16* __restrict__ W1t,
    const float* __restrict__ b1, const int* __restrict__ tok_list,
    const int* __restrict__ offsets, bf16* __restrict__ hbuf) {
    __shared__ bf16 As0[BM * 32];
    __shared__ bf16 As1[BM * 32];
    __shared__ bf16 Bs0[BM * 32];
    __shared__ bf16 Bs1[BM * 32];
    __shared__ int toks[BM];

    const int NCB = F_DIM / 128;          // 32
    const int per = (NUM_RB * NCB) / 8;   // 544
    const int flat = blockIdx.x;
    const int sw = (flat & 7) * per + (flat >> 3);
    const int rb = sw / NCB, cb = sw % NCB;

    const int row0 = rb * BM;
    const int total = offsets[E_NUM];
    if (row0 >= total) return;
    int e = 0;
#pragma unroll
    for (int i = 1; i < E_NUM; ++i) e += (row0 >= offsets[i]) ? 1 : 0;

    const int tid = threadIdx.x;
    if (tid < BM) toks[tid] = tok_list[row0 + tid];
    __syncthreads();   // full drain: vmcnt henceforth counts only stage loads

    const int lane = tid & 63;
    const int w = tid >> 6;
    const int f0 = cb * 128;

    const int r0 = w * 16 + (lane >> 2);
    const int r1 = 64 + w * 16 + (lane >> 2);
    const int c16 = (lane & 3) ^ ((lane >> 3) & 3);
    int t0 = toks[r0]; if (t0 < 0) t0 = 0;
    int t1 = toks[r1]; if (t1 < 0) t1 = 0;
    const bf16* aP0 = xb + (size_t)t0 * D_DIM + c16 * 8;
    const bf16* aP1 = xb + (size_t)t1 * D_DIM + c16 * 8;
    const bf16* bP0 = W1t + ((size_t)e * F_DIM + f0 + r0) * D_DIM + c16 * 8;
    const bf16* bP1 = W1t + ((size_t)e * F_DIM + f0 + r1) * D_DIM + c16 * 8;

    const unsigned dO0 = __builtin_amdgcn_readfirstlane(w * 1024);
    const unsigned dO1 = __builtin_amdgcn_readfirstlane(4096 + w * 1024);

    const int wrow = (w >> 1) * 64, wcol = (w & 1) * 64;
    const int fr = lane & 15;
    const int fkk = 8 * ((lane >> 4) ^ ((lane >> 1) & 3));

    float4v acc[4][4];
#pragma unroll
    for (int m = 0; m < 4; ++m)
#pragma unroll
        for (int n = 0; n < 4; ++n)
#pragma unroll
            for (int r = 0; r < 4; ++r) acc[m][n][r] = 0.f;

    auto stage = [&](int kt, bf16* A, bf16* B) {
        const int ko = kt * 32;
        gl_lds16(aP0 + ko, (bf16*)((char*)A + dO0));
        gl_lds16(aP1 + ko, (bf16*)((char*)A + dO1));
        gl_lds16(bP0 + ko, (bf16*)((char*)B + dO0));
        gl_lds16(bP1 + ko, (bf16*)((char*)B + dO1));
    };

    const int NKT = D_DIM / 32;  // 32
    stage(0, As0, Bs0);
    stage(1, As1, Bs1);
    for (int kt = 0; kt < NKT - 2; kt += 2) {
        PH("vmcnt(4)", As0, Bs0, true, kt + 2);
        PH("vmcnt(4)", As1, Bs1, true, kt + 3);
    }
    PH("vmcnt(4)", As0, Bs0, false, 0);
    PH("vmcnt(0)", As1, Bs1, false, 0);

#pragma unroll
    for (int n = 0; n < 4; ++n) {
        const int gcol = f0 + wcol + n * 16 + fr;
        const float bias = b1[e * F_DIM + gcol];
#pragma unroll
        for (int m = 0; m < 4; ++m) {
#pragma unroll
            for (int r = 0; r < 4; ++r) {
                const int grow = row0 + wrow + m * 16 + (lane >> 4) * 4 + r;
                float v = acc[m][n][r] + bias;
                v = fmaxf(v, 0.f);
                hbuf[(size_t)grow * F_DIM + gcol] = __float2bfloat16(v);
            }
        }
    }
}

// ---------------- GEMM2 (exact R4): 128², 2-buf counted vmcnt ----------------
__global__ __launch_bounds__(256, 4) void gemm2_kernel(
    const bf16* __restrict__ hbuf, const bf16* __restrict__ W2t,
    const float* __restrict__ b2, const int* __restrict__ tok_list,
    const float* __restrict__ gate_list, const int* __restrict__ offsets,
    float* __restrict__ out) {
    __shared__ bf16 As0[BM * 32];
    __shared__ bf16 As1[BM * 32];
    __shared__ bf16 Bs0[BM * 32];
    __shared__ bf16 Bs1[BM * 32];
    __shared__ int toks[BM];
    __shared__ float gates_s[BM];

    const int NCB = D_DIM / 128;          // 8
    const int per = (NUM_RB * NCB) / 8;   // 136
    const int flat = blockIdx.x;
    const int sw = (flat & 7) * per + (flat >> 3);
    const int rb = sw / NCB, cb = sw % NCB;

    const int row0 = rb * BM;
    const int total = offsets[E_NUM];
    if (row0 >= total) return;
    int e = 0;
#pragma unroll
    for (int i = 1; i < E_NUM; ++i) e += (row0 >= offsets[i]) ? 1 : 0;

    const int tid = threadIdx.x;
    if (tid < BM) {
        int t = tok_list[row0 + tid];
        toks[tid] = t;
        gates_s[tid] = (t >= 0) ? gate_list[row0 + tid] : 0.f;
    }
    __syncthreads();

    const int lane = tid & 63;
    const int w = tid >> 6;
    const int d0 = cb * 128;

    const int r0 = w * 16 + (lane >> 2);
    const int r1 = 64 + w * 16 + (lane >> 2);
    const int c16 = (lane & 3) ^ ((lane >> 3) & 3);
    const bf16* aP0 = hbuf + (size_t)(row0 + r0) * F_DIM + c16 * 8;
    const bf16* aP1 = hbuf + (size_t)(row0 + r1) * F_DIM + c16 * 8;
    const bf16* bP0 = W2t + ((size_t)e * D_DIM + d0 + r0) * F_DIM + c16 * 8;
    const bf16* bP1 = W2t + ((size_t)e * D_DIM + d0 + r1) * F_DIM + c16 * 8;

    const unsigned dO0 = __builtin_amdgcn_readfirstlane(w * 1024);
    const unsigned dO1 = __builtin_amdgcn_readfirstlane(4096 + w * 1024);

    const int wrow = (w >> 1) * 64, wcol = (w & 1) * 64;
    const int fr = lane & 15;
    const int fkk = 8 * ((lane >> 4) ^ ((lane >> 1) & 3));

    float4v acc[4][4];
#pragma unroll
    for (int m = 0; m < 4; ++m)
#pragma unroll
        for (int n = 0; n < 4; ++n)
#pragma unroll
            for (int r = 0; r < 4; ++r) acc[m][n][r] = 0.f;

    auto stage = [&](int kt, bf16* A, bf16* B) {
        const int ko = kt * 32;
        gl_lds16(aP0 + ko, (bf16*)((char*)A + dO0));
        gl_lds16(aP1 + ko, (bf16*)((char*)A + dO1));
        gl_lds16(bP0 + ko, (bf16*)((char*)B + dO0));
        gl_lds16(bP1 + ko, (bf16*)((char*)B + dO1));
    };

    const int NKT = F_DIM / 32;  // 128
    stage(0, As0, Bs0);
    stage(1, As1, Bs1);
    for (int kt = 0; kt < NKT - 2; kt += 2) {
        PH("vmcnt(4)", As0, Bs0, true, kt + 2);
        PH("vmcnt(4)", As1, Bs1, true, kt + 3);
    }
    PH("vmcnt(4)", As0, Bs0, false, 0);
    PH("vmcnt(0)", As1, Bs1, false, 0);

#pragma unroll
    for (int n = 0; n < 4; ++n) {
        const int gcol = d0 + wcol + n * 16 + fr;
        const float bias = b2[e * D_DIM + gcol];
#pragma unroll
        for (int m = 0; m < 4; ++m) {
#pragma unroll
            for (int r = 0; r < 4; ++r) {
                const int lrow = wrow + m * 16 + (lane >> 4) * 4 + r;
                const int t = toks[lrow];
                if (t >= 0) {
                    const float v = (acc[m][n][r] + bias) * gates_s[lrow];
                    atomicAdd(&out[(size_t)t * D_DIM + gcol], v);
                }
            }
        }
    }
}

extern "C" void kernel_launch(void* const* d_in, const int* in_sizes, int n_in,
                              void* d_out, int out_size, void* d_ws, size_t ws_size,
                              hipStream_t stream) {
    const float* x = (const float*)d_in[0];
    const float* Wg = (const float*)d_in[1];
    const float* bg = (const float*)d_in[2];
    const float* W1 = (const float*)d_in[3];
    const float* b1 = (const float*)d_in[4];
    const float* W2 = (const float*)d_in[5];
    const float* b2 = (const float*)d_in[6];
    float* out = (float*)d_out;

    char* ws = (char*)d_ws;
    int* counts = (int*)(ws + 0);       // 8 ints
    int* cursors = (int*)(ws + 32);     // 8 ints
    int* offsets = (int*)(ws + 64);     // 9 ints
    int* top_idx = (int*)(ws + 256);                     // T*2 ints
    float* top_gate = (float*)(ws + 256 + 65536);        // T*2 floats
    int* tok_list = (int*)(ws + 256 + 2 * 65536);        // MAX_ROWS ints
    float* gate_list = (float*)(ws + 256 + 2 * 65536 + 69632);
    size_t off = 256 + 2 * 65536 + 2 * 69632;            // 270592, 256-aligned
    bf16* xb = (bf16*)(ws + off);
    off += (size_t)T_TOK * D_DIM * 2;
    bf16* W1t = (bf16*)(ws + off);
    off += (size_t)E_NUM * D_DIM * F_DIM * 2;
    bf16* W2t = (bf16*)(ws + off);
    off += (size_t)E_NUM * D_DIM * F_DIM * 2;
    bf16* hbuf = (bf16*)(ws + off);

    hipMemsetAsync(d_out, 0, (size_t)T_TOK * D_DIM * sizeof(float), stream);
    hipMemsetAsync(ws, 0, 64, stream);                       // counts + cursors
    hipMemsetAsync(tok_list, 0xFF, (size_t)MAX_ROWS * 4, stream);  // -1 sentinels

    transpose_both<<<16384, 256, 0, stream>>>(W1, W1t, W2, W2t);
    router_xcvt_kernel<<<T_TOK / 4, 256, 0, stream>>>(x, Wg, bg, top_idx, top_gate,
                                                      counts, xb);
    scatter_kernel<<<T_TOK / 256, 256, 0, stream>>>(top_idx, top_gate, counts, offsets,
                                                    cursors, tok_list, gate_list);
    gemm1_kernel<<<NUM_RB * (F_DIM / 128), 256, 0, stream>>>(xb, W1t, b1, tok_list,
                                                             offsets, hbuf);
    gemm2_kernel<<<NUM_RB * (D_DIM / 128), 256, 0, stream>>>(hbuf, W2t, b2, tok_list,
                                                             gate_list, offsets, out);
}